// Round 2
// baseline (851.219 us; speedup 1.0000x reference)
//
#include <hip/hip_runtime.h>

// Problem constants (from reference)
#define ZDIM 64
#define CDIM 256
#define PDIM 4
#define BNODES 50000
#define LD 3
#define ROW (CDIM * LD)          // 768 f32 per (p,b) row
#define ALPHA 0.5f               // 1/sqrt(P) = 1/2

// One wave (64 lanes) per node b.  All tensors are float32 (per reference).
//  - lane z reads node_attrs[b,z]; ballot finds the one-hot index (Z == 64 == wave size)
//  - lane l owns 12 contiguous f32 (4 c's x 3 d's) of the 768-element row
__global__ __launch_bounds__(256) void ecwl_kernel(
    const float* __restrict__ t,    // [P][B][C][3]
    const float* __restrict__ na,   // [B][Z]  (one-hot)
    const float* __restrict__ w,    // [Z][C][P]
    float* __restrict__ out)        // [B][C][3]
{
    const int wave = threadIdx.x >> 6;
    const int lane = threadIdx.x & 63;
    const int b = blockIdx.x * 4 + wave;
    if (b >= BNODES) return;

    // ---- one-hot index via wave ballot (coalesced 4B/lane read) ----
    float nav = na[(size_t)b * ZDIM + lane];
    unsigned long long m = __ballot(nav > 0.5f);
    int idx = (m != 0ull) ? (__ffsll(m) - 1) : 0;   // clamp: never fault on bad input

    // ---- weights for this lane's 4 c's: W[idx][c0..c0+3][0..3] = 16 f32 = 64 B ----
    // wave-uniform idx -> coalesced; one z-slice is 4 KB -> L1-resident across waves
    const int c0 = lane * 4;
    const float4* wp = (const float4*)(w + (size_t)idx * (CDIM * PDIM) + (size_t)c0 * PDIM);
    float4 w0 = wp[0];
    float4 w1 = wp[1];
    float4 w2 = wp[2];
    float4 w3 = wp[3];
    const float wf[16] = { w0.x, w0.y, w0.z, w0.w,
                           w1.x, w1.y, w1.z, w1.w,
                           w2.x, w2.y, w2.z, w2.w,
                           w3.x, w3.y, w3.z, w3.w };

    float acc[12];
    #pragma unroll
    for (int j = 0; j < 12; ++j) acc[j] = 0.0f;

    const int e0 = lane * 12;   // f32 offset within the 768-element row (48 B, 16B-aligned)

    #pragma unroll
    for (int p = 0; p < PDIM; ++p) {
        const float4* tp = (const float4*)(t + ((size_t)p * BNODES + b) * ROW + e0);
        float4 a0 = tp[0];
        float4 a1 = tp[1];
        float4 a2 = tp[2];
        const float tv[12] = { a0.x, a0.y, a0.z, a0.w,
                               a1.x, a1.y, a1.z, a1.w,
                               a2.x, a2.y, a2.z, a2.w };
        #pragma unroll
        for (int j = 0; j < 12; ++j) {
            const int cc = j / 3;               // compile-time after unroll
            acc[j] = fmaf(wf[cc * 4 + p], tv[j], acc[j]);
        }
    }

    // ---- scale and store (3 x float4 = 48 B, coalesced across the wave) ----
    float4* op = (float4*)(out + (size_t)b * ROW + e0);
    op[0] = make_float4(acc[0] * ALPHA, acc[1] * ALPHA, acc[2]  * ALPHA, acc[3]  * ALPHA);
    op[1] = make_float4(acc[4] * ALPHA, acc[5] * ALPHA, acc[6]  * ALPHA, acc[7]  * ALPHA);
    op[2] = make_float4(acc[8] * ALPHA, acc[9] * ALPHA, acc[10] * ALPHA, acc[11] * ALPHA);
}

extern "C" void kernel_launch(void* const* d_in, const int* in_sizes, int n_in,
                              void* d_out, int out_size, void* d_ws, size_t ws_size,
                              hipStream_t stream) {
    const float* t  = (const float*)d_in[0];   // [P,B,C,3]
    const float* na = (const float*)d_in[1];   // [B,Z]
    const float* w  = (const float*)d_in[2];   // [Z,C,P]
    float* out = (float*)d_out;                // [B,C,3]

    // 4 waves per block, one wave per node: 50000 / 4 = 12500 blocks exactly
    dim3 grid((BNODES + 3) / 4);
    dim3 block(256);
    ecwl_kernel<<<grid, block, 0, stream>>>(t, na, w, out);
}